// Round 1
// baseline (304.626 us; speedup 1.0000x reference)
//
#include <hip/hip_runtime.h>

// out[c,n,o] = sum_i x[c,n,i] * W[model_idx[c],i,o] + B[int(t[c]*31),o]
// x[64,2048,256] f32, W[64,256,256] f32, B[32,256] f32, out f32.
//
// v2: latency-bound fix. Previous kernel was barrier-serialized (2 syncthreads
// per 32-k step around an X staging chain) at 2 blocks/CU -> 36% of HBM BW.
// New structure:
//   kernel 1 (wt_k): Wt[c][n][k] = bf16(W[MI[c]][k][n]) into workspace (8.4 MB),
//                    LDS-transposed, coalesced both sides. Runs once, ~5 us.
//   kernel 2 (gemm_k): zero LDS, zero barriers. A-fragments loaded directly
//                    from global X (32B contiguous per lane, 16x128B segments
//                    per wave), cvt f32->bf16 in-register; B-fragments are 16B
//                    contiguous loads from L2-resident Wt. Waves pipeline loads
//                    across K freely -> continuous HBM streaming.
// Fallback to the previous proven kernel if ws_size < 8.4 MB.

#define M_PTS 2048
#define K_DIM 256
#define N_DIM 256
#define BT_STRIDE 264
#define WT_BYTES ((size_t)64 * K_DIM * N_DIM * 2)

typedef float floatx4 __attribute__((ext_vector_type(4)));
typedef __bf16 bf16x4 __attribute__((ext_vector_type(4)));
typedef __bf16 bf16x8 __attribute__((ext_vector_type(8)));

__device__ __forceinline__ __bf16 cvt_bf16(float f) {
  // round-to-nearest-even f32 -> bf16 (finite inputs), branch-free
  unsigned u = __builtin_bit_cast(unsigned, f);
  unsigned r = (u + 0x7FFFu + ((u >> 16) & 1u)) >> 16;
  return __builtin_bit_cast(__bf16, (unsigned short)r);
}

// ---- pre-pass: gather + transpose + cvt W into workspace --------------------
// grid 1024: one 64x64 tile each. Loads coalesced along n, stores coalesced
// along k (128B/wave). LDS tile padded [64][65] -> 2-way max (free).
__global__ __launch_bounds__(256) void wt_k(const float* __restrict__ W,
                                            const int* __restrict__ MI,
                                            __bf16* __restrict__ Wt) {
  __shared__ float tile[64][65];
  const int bid = blockIdx.x;
  const int c  = bid >> 4;
  const int kt = (bid >> 2) & 3;
  const int nt = bid & 3;
  const float* __restrict__ src =
      W + (size_t)MI[c] * (K_DIM * N_DIM) + (size_t)(kt * 64) * N_DIM + nt * 64;
  __bf16* __restrict__ dst =
      Wt + (size_t)c * (K_DIM * N_DIM) + (size_t)(nt * 64) * K_DIM + kt * 64;
  const int tid = threadIdx.x;
  {
    const int nl = tid & 63, kl0 = tid >> 6;
#pragma unroll
    for (int u = 0; u < 16; ++u)
      tile[kl0 + u * 4][nl] = src[(size_t)(kl0 + u * 4) * N_DIM + nl];
  }
  __syncthreads();
  {
    const int kl = tid & 63, nl0 = tid >> 6;
#pragma unroll
    for (int u = 0; u < 16; ++u)
      dst[(size_t)(nl0 + u * 4) * K_DIM + kl] = cvt_bf16(tile[kl][nl0 + u * 4]);
  }
}

// ---- main: barrier-free, LDS-free MFMA GEMM --------------------------------
// 2048 blocks: c = bid>>5, mg = (bid>>1)&15, nt = bid&1 (n-twins adjacent so
// the shared X tile is L2/L3-hot). 256 thr = 2x2 waves, 64x64 out per wave.
__global__ __launch_bounds__(256) void gemm_k(const float* __restrict__ X,
                                              const float* __restrict__ T,
                                              const __bf16* __restrict__ Wt,
                                              const float* __restrict__ Bb,
                                              float* __restrict__ Out) {
  const int bid = blockIdx.x;
  const int c   = bid >> 5;
  const int mg  = (bid >> 1) & 15;
  const int nt  = bid & 1;
  const int n0  = nt * 128;
  const int m0  = mg * 128;

  const int tid  = threadIdx.x;
  const int lane = tid & 63;
  const int w    = tid >> 6;
  const int wm   = w & 1;      // 2x2 wave grid
  const int wn   = w >> 1;
  const int r    = lane & 15;  // fragment row/col
  const int kg   = lane >> 4;  // k-group 0..3

  const float*  __restrict__ Xc = X  + (size_t)c * (M_PTS * K_DIM);
  const __bf16* __restrict__ Wc = Wt + (size_t)c * (K_DIM * N_DIM);

  const float* xa[4];
  const __bf16* wb[4];
#pragma unroll
  for (int i = 0; i < 4; ++i)
    xa[i] = Xc + (size_t)(m0 + wm * 64 + i * 16 + r) * K_DIM + kg * 8;
#pragma unroll
  for (int j = 0; j < 4; ++j)
    wb[j] = Wc + (size_t)(n0 + wn * 64 + j * 16 + r) * K_DIM + kg * 8;

  // bias (fp32, exact): idx = trunc(t[c]*31)
  int bidx = (int)(T[c] * 31.0f);
  bidx = bidx < 0 ? 0 : (bidx > 31 ? 31 : bidx);
  const float* __restrict__ brow = Bb + bidx * N_DIM + n0 + wn * 64;
  float bv[4];
#pragma unroll
  for (int j = 0; j < 4; ++j) bv[j] = brow[j * 16 + r];

  floatx4 acc[4][4] = {};

#pragma unroll 2
  for (int kt = 0; kt < 8; ++kt) {
    const int k0 = kt * 32;
    floatx4 f0[4], f1[4];
    bf16x8 b[4];
#pragma unroll
    for (int i = 0; i < 4; ++i) {
      f0[i] = *(const floatx4*)(xa[i] + k0);
      f1[i] = *(const floatx4*)(xa[i] + k0 + 4);
    }
#pragma unroll
    for (int j = 0; j < 4; ++j) b[j] = *(const bf16x8*)(wb[j] + k0);
    bf16x8 a[4];
#pragma unroll
    for (int i = 0; i < 4; ++i)
#pragma unroll
      for (int v = 0; v < 4; ++v) {
        a[i][v]     = cvt_bf16(f0[i][v]);
        a[i][v + 4] = cvt_bf16(f1[i][v]);
      }
#pragma unroll
    for (int i = 0; i < 4; ++i)
#pragma unroll
      for (int j = 0; j < 4; ++j)
        acc[i][j] = __builtin_amdgcn_mfma_f32_16x16x32_bf16(a[i], b[j], acc[i][j], 0, 0, 0);
  }

  // C/D layout: col=lane&15, row=(lane>>4)*4+reg [m89/m91]
  float* __restrict__ Oc = Out + (size_t)c * (M_PTS * N_DIM);
#pragma unroll
  for (int i = 0; i < 4; ++i) {
#pragma unroll
    for (int j = 0; j < 4; ++j) {
      const int col = n0 + wn * 64 + j * 16 + r;
#pragma unroll
      for (int v = 0; v < 4; ++v) {
        const int row = m0 + wm * 64 + i * 16 + kg * 4 + v;
        Oc[(size_t)row * N_DIM + col] = acc[i][j][v] + bv[j];
      }
    }
  }
}

// ---- fallback: previous proven kernel (used only if workspace too small) ---
__global__ __launch_bounds__(256) void fused_k(
    const float* __restrict__ X, const float* __restrict__ T,
    const int* __restrict__ MI, const float* __restrict__ W,
    const float* __restrict__ Bb, float* __restrict__ Out) {
  __shared__ __bf16 As[128 * 32];
  __shared__ __bf16 Bt[128 * BT_STRIDE];

  const int bid = blockIdx.x;
  const int c   = bid >> 4;
  const int mg  = (bid >> 1) & 7;
  const int nt  = bid & 1;
  const int n0  = nt * 128;

  const float* __restrict__ Xc = X + (size_t)c * (M_PTS * K_DIM);
  const float* __restrict__ Wc = W + (size_t)MI[c] * (K_DIM * N_DIM);

  const int tid  = threadIdx.x;
  const int lane = tid & 63;
  const int w    = tid >> 6;
  const int wm   = w & 1;
  const int wn   = w >> 1;
  const int r    = lane & 15;
  const int kg   = lane >> 4;

  {
    const int n  = tid & 127;
    const int kq = tid >> 7;
    const float* __restrict__ src = Wc + (size_t)(kq * 128) * N_DIM + n0 + n;
    __bf16* __restrict__ dst = &Bt[n * BT_STRIDE + kq * 128];
#pragma unroll 4
    for (int u = 0; u < 32; ++u) {
      bf16x4 v;
      v.x = cvt_bf16(src[(size_t)(u * 4 + 0) * N_DIM]);
      v.y = cvt_bf16(src[(size_t)(u * 4 + 1) * N_DIM]);
      v.z = cvt_bf16(src[(size_t)(u * 4 + 2) * N_DIM]);
      v.w = cvt_bf16(src[(size_t)(u * 4 + 3) * N_DIM]);
      *(bf16x4*)&dst[u * 4] = v;
    }
  }

  const int sm  = tid >> 1;
  const int skh = (tid & 1) * 16;
  const float* __restrict__ xrow = Xc + skh;
  __bf16* __restrict__ adst = &As[sm * 32 + skh];

  int bidx = (int)(T[c] * 31.0f);
  bidx = bidx < 0 ? 0 : (bidx > 31 ? 31 : bidx);
  const float* __restrict__ brow = Bb + bidx * N_DIM + n0 + wn * 64;
  float bv[4];
#pragma unroll
  for (int j = 0; j < 4; ++j) bv[j] = brow[j * 16 + r];

  float* __restrict__ Oc = Out + (size_t)c * (M_PTS * N_DIM);

  for (int mt2 = 0; mt2 < 2; ++mt2) {
    const int m0 = mg * 256 + mt2 * 128;
    const float* __restrict__ xsrc = xrow + (size_t)(m0 + sm) * K_DIM;
    floatx4 acc[4][4] = {};

    for (int kt = 0; kt < 8; ++kt) {
      const int k0 = kt * 32;
      __syncthreads();
      {
        floatx4 f0 = *(const floatx4*)(xsrc + k0 + 0);
        floatx4 f1 = *(const floatx4*)(xsrc + k0 + 4);
        floatx4 f2 = *(const floatx4*)(xsrc + k0 + 8);
        floatx4 f3 = *(const floatx4*)(xsrc + k0 + 12);
        bf16x8 h0, h1;
#pragma unroll
        for (int v = 0; v < 4; ++v) {
          h0[v]     = cvt_bf16(f0[v]);
          h0[v + 4] = cvt_bf16(f1[v]);
          h1[v]     = cvt_bf16(f2[v]);
          h1[v + 4] = cvt_bf16(f3[v]);
        }
        *(bf16x8*)&adst[0] = h0;
        *(bf16x8*)&adst[8] = h1;
      }
      __syncthreads();

      bf16x8 a[4], b[4];
#pragma unroll
      for (int i = 0; i < 4; ++i)
        a[i] = *(const bf16x8*)&As[(wm * 64 + i * 16 + r) * 32 + kg * 8];
#pragma unroll
      for (int j = 0; j < 4; ++j)
        b[j] = *(const bf16x8*)&Bt[(wn * 64 + j * 16 + r) * BT_STRIDE + k0 + kg * 8];
#pragma unroll
      for (int i = 0; i < 4; ++i)
#pragma unroll
        for (int j = 0; j < 4; ++j)
          acc[i][j] = __builtin_amdgcn_mfma_f32_16x16x32_bf16(a[i], b[j], acc[i][j], 0, 0, 0);
    }

#pragma unroll
    for (int i = 0; i < 4; ++i) {
#pragma unroll
      for (int j = 0; j < 4; ++j) {
        const int col = n0 + wn * 64 + j * 16 + r;
#pragma unroll
        for (int v = 0; v < 4; ++v) {
          const int row = m0 + wm * 64 + i * 16 + kg * 4 + v;
          Oc[(size_t)row * N_DIM + col] = acc[i][j][v] + bv[j];
        }
      }
    }
  }
}

extern "C" void kernel_launch(void* const* d_in, const int* in_sizes, int n_in,
                              void* d_out, int out_size, void* d_ws, size_t ws_size,
                              hipStream_t stream) {
  const float* X   = (const float*)d_in[0];  // x [64,2048,256]
  const float* T   = (const float*)d_in[1];  // t [64]
  const int* MI    = (const int*)d_in[2];    // model_idx [64]
  const float* W   = (const float*)d_in[3];  // W [64,256,256]
  const float* Bb  = (const float*)d_in[4];  // B [32,256]
  float* Out       = (float*)d_out;

  if (ws_size >= WT_BYTES && d_ws != nullptr) {
    __bf16* Wt = (__bf16*)d_ws;
    wt_k<<<dim3(1024), dim3(256), 0, stream>>>(W, MI, Wt);
    gemm_k<<<dim3(2048), dim3(256), 0, stream>>>(X, T, Wt, Bb, Out);
  } else {
    fused_k<<<dim3(1024), dim3(256), 0, stream>>>(X, T, MI, W, Bb, Out);
  }
}

// Round 2
// 274.299 us; speedup vs baseline: 1.1106x; 1.1106x over previous
//
#include <hip/hip_runtime.h>

// out[c,n,o] = sum_i x[c,n,i] * W[model_idx[c],i,o] + B[int(t[c]*31),o]
// x[64,2048,256] f32, W[64,256,256] f32, B[32,256] f32, out f32.
//
// v3: combine the two proven pieces.
//  - wt_k prepass (v2, kept): Wt[c][n][k] = bf16(W[MI[c]][k][n]) in workspace
//    (8.4 MB, L2-resident). B-fragments = 16B global loads, NO Bt LDS, no
//    per-block W gather.
//  - A staged cooperatively like fused_k but via global_load_lds width=16
//    (no VGPR round trip), fp32, DOUBLE-BUFFERED (2x16 KB), ONE barrier per
//    k-step: barrier -> STAGE(kt+1, buf^1) -> compute buf[cur]. The vmcnt(0)
//    drain at the next barrier gives prefetch-depth-1: stage latency hides
//    under a full compute phase. 32 KB LDS + launch_bounds(256,4) -> 4
//    blocks/CU for inter-block overlap.
//  - LDS XOR swizzle, both-sides (rule #21): gload_lds dest stays linear,
//    global SOURCE chunk is pre-permuted (lc^l8), read applies the same XOR
//    ((r&7)<<4 on the byte col) -> ds_read_b128 at its 8-cy floor instead of
//    16-way conflict.
//  - XCD-chunked remap: n-twin blocks (sharing an X tile) land on the same
//    XCD's L2.

#define M_PTS 2048
#define K_DIM 256
#define N_DIM 256
#define BT_STRIDE 264
#define WT_BYTES ((size_t)64 * K_DIM * N_DIM * 2)

typedef float floatx4 __attribute__((ext_vector_type(4)));
typedef __bf16 bf16x4 __attribute__((ext_vector_type(4)));
typedef __bf16 bf16x8 __attribute__((ext_vector_type(8)));

typedef __attribute__((address_space(3))) void lds_void;
typedef const __attribute__((address_space(1))) void gbl_void;

__device__ __forceinline__ __bf16 cvt_bf16(float f) {
  // round-to-nearest-even f32 -> bf16 (finite inputs), branch-free
  unsigned u = __builtin_bit_cast(unsigned, f);
  unsigned r = (u + 0x7FFFu + ((u >> 16) & 1u)) >> 16;
  return __builtin_bit_cast(__bf16, (unsigned short)r);
}

// ---- pre-pass: gather + transpose + cvt W into workspace --------------------
__global__ __launch_bounds__(256) void wt_k(const float* __restrict__ W,
                                            const int* __restrict__ MI,
                                            __bf16* __restrict__ Wt) {
  __shared__ float tile[64][65];
  const int bid = blockIdx.x;
  const int c  = bid >> 4;
  const int kt = (bid >> 2) & 3;
  const int nt = bid & 3;
  const float* __restrict__ src =
      W + (size_t)MI[c] * (K_DIM * N_DIM) + (size_t)(kt * 64) * N_DIM + nt * 64;
  __bf16* __restrict__ dst =
      Wt + (size_t)c * (K_DIM * N_DIM) + (size_t)(nt * 64) * K_DIM + kt * 64;
  const int tid = threadIdx.x;
  {
    const int nl = tid & 63, kl0 = tid >> 6;
#pragma unroll
    for (int u = 0; u < 16; ++u)
      tile[kl0 + u * 4][nl] = src[(size_t)(kl0 + u * 4) * N_DIM + nl];
  }
  __syncthreads();
  {
    const int kl = tid & 63, nl0 = tid >> 6;
#pragma unroll
    for (int u = 0; u < 16; ++u)
      dst[(size_t)(nl0 + u * 4) * K_DIM + kl] = cvt_bf16(tile[kl][nl0 + u * 4]);
  }
}

// ---- main: A dbuf via global_load_lds, B from L2-resident Wt ---------------
// 2048 blocks, each 128 rows x 128 cols. 2x2 waves, 64x64 out per wave.
__global__ __launch_bounds__(256, 4) void gemm_k(const float* __restrict__ X,
                                                 const float* __restrict__ T,
                                                 const __bf16* __restrict__ Wt,
                                                 const float* __restrict__ Bb,
                                                 float* __restrict__ Out) {
  __shared__ float As[2][128 * 32];  // [buf][row][k] fp32, 16 KB each

  // XCD-chunked remap: hw bid -> xcd = bid&7, slot = bid>>3; logical
  // wg = xcd*256 + slot keeps logical twins (2p,2p+1) on one XCD.
  const int bid = blockIdx.x;
  const int wg  = ((bid & 7) << 8) | (bid >> 3);
  const int c   = wg >> 5;
  const int mg  = (wg >> 1) & 15;
  const int nt  = wg & 1;
  const int n0  = nt * 128;
  const int m0  = mg * 128;

  const int tid  = threadIdx.x;
  const int lane = tid & 63;
  const int w    = tid >> 6;
  const int wm   = w & 1;      // 2x2 wave grid
  const int wn   = w >> 1;
  const int r    = lane & 15;  // fragment row/col
  const int kg   = lane >> 4;  // k-group 0..3

  const float*  __restrict__ Xc = X  + (size_t)c * (M_PTS * K_DIM);
  const __bf16* __restrict__ Wc = Wt + (size_t)c * (K_DIM * N_DIM);

  // ---- staging geometry: wave w covers rows [w*32, w*32+32), 4 issues of
  // 8 rows x 128B. Lane l -> row w*32+u*8+(l>>3), physical 16B chunk (l&7).
  // Source chunk pre-permuted: logical chunk = (l&7) ^ (l>>3) so the
  // swizzled read finds its data (involution, row&7 == l>>3 here).
  const int l8 = lane >> 3;
  const int lc = lane & 7;
  const float* __restrict__ xbase =
      Xc + (size_t)(m0 + w * 32 + l8) * K_DIM + ((lc ^ l8) << 2);
  const int lbase = (w * 32 + l8) * 32 + lc * 4;  // float index into As[buf]

#define STAGE(kt_, buf_)                                                      \
  {                                                                           \
    _Pragma("unroll") for (int u = 0; u < 4; ++u) {                           \
      __builtin_amdgcn_global_load_lds(                                       \
          (gbl_void*)(xbase + (size_t)u * 8 * K_DIM + (kt_) * 32),            \
          (lds_void*)(&As[buf_][lbase + u * 256]), 16, 0, 0);                 \
    }                                                                         \
  }

  // B fragment pointers: Wt row (n) is K-contiguous bf16; 16B per (j,kt).
  const __bf16* __restrict__ wb[4];
#pragma unroll
  for (int j = 0; j < 4; ++j)
    wb[j] = Wc + (size_t)(n0 + wn * 64 + j * 16 + r) * K_DIM + kg * 8;

  // bias (fp32, exact): idx = trunc(t[c]*31)
  int bidx = (int)(T[c] * 31.0f);
  bidx = bidx < 0 ? 0 : (bidx > 31 ? 31 : bidx);
  const float* __restrict__ brow = Bb + bidx * N_DIM + n0 + wn * 64;
  float bv[4];
#pragma unroll
  for (int j = 0; j < 4; ++j) bv[j] = brow[j * 16 + r];

  floatx4 acc[4][4] = {};

  STAGE(0, 0);
  int cur = 0;

  for (int kt = 0; kt < 8; ++kt) {
    __syncthreads();  // vmcnt drain -> As[cur] ready; prior reads of cur^1 done
    if (kt < 7) STAGE(kt + 1, cur ^ 1);

    // B loads (global, L2-resident Wt), issued before LDS reads
    bf16x8 b[4];
#pragma unroll
    for (int j = 0; j < 4; ++j) b[j] = *(const bf16x8*)(wb[j] + kt * 32);

    // A fragments from swizzled LDS: logical float col kg*8..+7 of row
    // wm*64+i*16+r; physical byte = logical_byte ^ ((r&7)<<4).
    bf16x8 a[4];
#pragma unroll
    for (int i = 0; i < 4; ++i) {
      const int row = wm * 64 + i * 16 + r;
      const int p0  = ((kg * 32) ^ ((r & 7) << 4)) >> 2;  // float idx of 1st 16B
      const floatx4 f0 = *(const floatx4*)&As[cur][row * 32 + p0];
      const floatx4 f1 = *(const floatx4*)&As[cur][row * 32 + (p0 ^ 4)];
#pragma unroll
      for (int v = 0; v < 4; ++v) {
        a[i][v]     = cvt_bf16(f0[v]);
        a[i][v + 4] = cvt_bf16(f1[v]);
      }
    }

#pragma unroll
    for (int i = 0; i < 4; ++i)
#pragma unroll
      for (int j = 0; j < 4; ++j)
        acc[i][j] = __builtin_amdgcn_mfma_f32_16x16x32_bf16(a[i], b[j], acc[i][j], 0, 0, 0);

    cur ^= 1;
  }

  // C/D layout: col=lane&15, row=(lane>>4)*4+reg [m89/m91]
  float* __restrict__ Oc = Out + (size_t)c * (M_PTS * N_DIM);
#pragma unroll
  for (int i = 0; i < 4; ++i) {
#pragma unroll
    for (int j = 0; j < 4; ++j) {
      const int col = n0 + wn * 64 + j * 16 + r;
#pragma unroll
      for (int v = 0; v < 4; ++v) {
        const int row = m0 + wm * 64 + i * 16 + kg * 4 + v;
        Oc[(size_t)row * N_DIM + col] = acc[i][j][v] + bv[j];
      }
    }
  }
#undef STAGE
}

// ---- fallback: previous proven kernel (used only if workspace too small) ---
__global__ __launch_bounds__(256) void fused_k(
    const float* __restrict__ X, const float* __restrict__ T,
    const int* __restrict__ MI, const float* __restrict__ W,
    const float* __restrict__ Bb, float* __restrict__ Out) {
  __shared__ __bf16 As[128 * 32];
  __shared__ __bf16 Bt[128 * BT_STRIDE];

  const int bid = blockIdx.x;
  const int c   = bid >> 4;
  const int mg  = (bid >> 1) & 7;
  const int nt  = bid & 1;
  const int n0  = nt * 128;

  const float* __restrict__ Xc = X + (size_t)c * (M_PTS * K_DIM);
  const float* __restrict__ Wc = W + (size_t)MI[c] * (K_DIM * N_DIM);

  const int tid  = threadIdx.x;
  const int lane = tid & 63;
  const int w    = tid >> 6;
  const int wm   = w & 1;
  const int wn   = w >> 1;
  const int r    = lane & 15;
  const int kg   = lane >> 4;

  {
    const int n  = tid & 127;
    const int kq = tid >> 7;
    const float* __restrict__ src = Wc + (size_t)(kq * 128) * N_DIM + n0 + n;
    __bf16* __restrict__ dst = &Bt[n * BT_STRIDE + kq * 128];
#pragma unroll 4
    for (int u = 0; u < 32; ++u) {
      bf16x4 v;
      v.x = cvt_bf16(src[(size_t)(u * 4 + 0) * N_DIM]);
      v.y = cvt_bf16(src[(size_t)(u * 4 + 1) * N_DIM]);
      v.z = cvt_bf16(src[(size_t)(u * 4 + 2) * N_DIM]);
      v.w = cvt_bf16(src[(size_t)(u * 4 + 3) * N_DIM]);
      *(bf16x4*)&dst[u * 4] = v;
    }
  }

  const int sm  = tid >> 1;
  const int skh = (tid & 1) * 16;
  const float* __restrict__ xrow = Xc + skh;
  __bf16* __restrict__ adst = &As[sm * 32 + skh];

  int bidx = (int)(T[c] * 31.0f);
  bidx = bidx < 0 ? 0 : (bidx > 31 ? 31 : bidx);
  const float* __restrict__ brow = Bb + bidx * N_DIM + n0 + wn * 64;
  float bv[4];
#pragma unroll
  for (int j = 0; j < 4; ++j) bv[j] = brow[j * 16 + r];

  float* __restrict__ Oc = Out + (size_t)c * (M_PTS * N_DIM);

  for (int mt2 = 0; mt2 < 2; ++mt2) {
    const int m0 = mg * 256 + mt2 * 128;
    const float* __restrict__ xsrc = xrow + (size_t)(m0 + sm) * K_DIM;
    floatx4 acc[4][4] = {};

    for (int kt = 0; kt < 8; ++kt) {
      const int k0 = kt * 32;
      __syncthreads();
      {
        floatx4 f0 = *(const floatx4*)(xsrc + k0 + 0);
        floatx4 f1 = *(const floatx4*)(xsrc + k0 + 4);
        floatx4 f2 = *(const floatx4*)(xsrc + k0 + 8);
        floatx4 f3 = *(const floatx4*)(xsrc + k0 + 12);
        bf16x8 h0, h1;
#pragma unroll
        for (int v = 0; v < 4; ++v) {
          h0[v]     = cvt_bf16(f0[v]);
          h0[v + 4] = cvt_bf16(f1[v]);
          h1[v]     = cvt_bf16(f2[v]);
          h1[v + 4] = cvt_bf16(f3[v]);
        }
        *(bf16x8*)&adst[0] = h0;
        *(bf16x8*)&adst[8] = h1;
      }
      __syncthreads();

      bf16x8 a[4], b[4];
#pragma unroll
      for (int i = 0; i < 4; ++i)
        a[i] = *(const bf16x8*)&As[(wm * 64 + i * 16 + r) * 32 + kg * 8];
#pragma unroll
      for (int j = 0; j < 4; ++j)
        b[j] = *(const bf16x8*)&Bt[(wn * 64 + j * 16 + r) * BT_STRIDE + k0 + kg * 8];
#pragma unroll
      for (int i = 0; i < 4; ++i)
#pragma unroll
        for (int j = 0; j < 4; ++j)
          acc[i][j] = __builtin_amdgcn_mfma_f32_16x16x32_bf16(a[i], b[j], acc[i][j], 0, 0, 0);
    }

#pragma unroll
    for (int i = 0; i < 4; ++i) {
#pragma unroll
      for (int j = 0; j < 4; ++j) {
        const int col = n0 + wn * 64 + j * 16 + r;
#pragma unroll
        for (int v = 0; v < 4; ++v) {
          const int row = m0 + wm * 64 + i * 16 + kg * 4 + v;
          Oc[(size_t)row * N_DIM + col] = acc[i][j][v] + bv[j];
        }
      }
    }
  }
}

extern "C" void kernel_launch(void* const* d_in, const int* in_sizes, int n_in,
                              void* d_out, int out_size, void* d_ws, size_t ws_size,
                              hipStream_t stream) {
  const float* X   = (const float*)d_in[0];  // x [64,2048,256]
  const float* T   = (const float*)d_in[1];  // t [64]
  const int* MI    = (const int*)d_in[2];    // model_idx [64]
  const float* W   = (const float*)d_in[3];  // W [64,256,256]
  const float* Bb  = (const float*)d_in[4];  // B [32,256]
  float* Out       = (float*)d_out;

  if (ws_size >= WT_BYTES && d_ws != nullptr) {
    __bf16* Wt = (__bf16*)d_ws;
    wt_k<<<dim3(1024), dim3(256), 0, stream>>>(W, MI, Wt);
    gemm_k<<<dim3(2048), dim3(256), 0, stream>>>(X, T, Wt, Bb, Out);
  } else {
    fused_k<<<dim3(1024), dim3(256), 0, stream>>>(X, T, MI, W, Bb, Out);
  }
}

// Round 4
// 265.782 us; speedup vs baseline: 1.1462x; 1.0320x over previous
//
#include <hip/hip_runtime.h>

// out[c,n,o] = sum_i x[c,n,i] * W[model_idx[c],i,o] + B[int(t[c]*31),o]
// x[64,2048,256] f32, W[64,256,256] f32, B[32,256] f32, out f32.
//
// v5: depth-2 software pipeline with FULLY PINNED issue order.
// v4's race: B-loads were plain C++ loads, so the compiler's placement broke
// the static vmcnt counts. Here every vmcnt-counted op is pinned:
//   - STAGE = 4x global_load_lds builtin (width 16), fenced by empty
//     memory-clobber asm.
//   - B(kt) = 4x inline-asm volatile global_load_dwordx4 (ordered among
//     themselves and vs fences).
// Per-step issue order (all 8 steps hand-unrolled, counts static):
//   s_waitcnt vmcnt(VTOP) lgkmcnt(0); sched_barrier; s_barrier;
//   STAGE(s+2); B(s+1); ds_read A(s); s_waitcnt vmcnt(VMFMA) lgkmcnt(0);
//   sched_barrier; cvt_pk + 16 MFMA.
// VTOP: after STAGE(s) come B(s-2),STAGE(s+1),B(s-1) = 12 (8 at s=0,7).
// VMFMA: after B(s) come STAGE(s+2),B(s+1) = 8 (4 at s=6, 0 at s=7).
// B regs double-buffered by step parity (b0/b1) -> no cross-fence v_movs.
// Bias/T loads AFTER the loop so no stray vmem enters the counts.
// wt_k prepass kept: Wt[c][n][k] bf16 in workspace; B-frags 16B L2-resident.

#define M_PTS 2048
#define K_DIM 256
#define N_DIM 256
#define BT_STRIDE 264
#define WT_BYTES ((size_t)64 * K_DIM * N_DIM * 2)

typedef float floatx4 __attribute__((ext_vector_type(4)));
typedef unsigned uintx4 __attribute__((ext_vector_type(4)));
typedef __bf16 bf16x4 __attribute__((ext_vector_type(4)));
typedef __bf16 bf16x8 __attribute__((ext_vector_type(8)));

typedef __attribute__((address_space(3))) void lds_void;
typedef const __attribute__((address_space(1))) void gbl_void;

__device__ __forceinline__ __bf16 cvt_bf16(float f) {
  unsigned u = __builtin_bit_cast(unsigned, f);
  unsigned r = (u + 0x7FFFu + ((u >> 16) & 1u)) >> 16;
  return __builtin_bit_cast(__bf16, (unsigned short)r);
}

__device__ __forceinline__ unsigned cvt_pk(float lo, float hi) {
  // v_cvt_pk_bf16_f32: RNE, packs {lo,hi} -> {bits15:0, bits31:16}
  unsigned d;
  asm("v_cvt_pk_bf16_f32 %0, %1, %2" : "=v"(d) : "v"(lo), "v"(hi));
  return d;
}

// ---- pre-pass: gather + transpose + cvt W into workspace --------------------
__global__ __launch_bounds__(256) void wt_k(const float* __restrict__ W,
                                            const int* __restrict__ MI,
                                            __bf16* __restrict__ Wt) {
  __shared__ float tile[64][65];
  const int bid = blockIdx.x;
  const int c  = bid >> 4;
  const int kt = (bid >> 2) & 3;
  const int nt = bid & 3;
  const float* __restrict__ src =
      W + (size_t)MI[c] * (K_DIM * N_DIM) + (size_t)(kt * 64) * N_DIM + nt * 64;
  __bf16* __restrict__ dst =
      Wt + (size_t)c * (K_DIM * N_DIM) + (size_t)(nt * 64) * K_DIM + kt * 64;
  const int tid = threadIdx.x;
  {
    const int nl = tid & 63, kl0 = tid >> 6;
#pragma unroll
    for (int u = 0; u < 16; ++u)
      tile[kl0 + u * 4][nl] = src[(size_t)(kl0 + u * 4) * N_DIM + nl];
  }
  __syncthreads();
  {
    const int kl = tid & 63, nl0 = tid >> 6;
#pragma unroll
    for (int u = 0; u < 16; ++u)
      dst[(size_t)(nl0 + u * 4) * K_DIM + kl] = cvt_bf16(tile[kl][nl0 + u * 4]);
  }
}

// ---- main: depth-2 staged A (3 LDS bufs), pinned counted waits -------------
__global__ __launch_bounds__(256, 3) void gemm_k(const float* __restrict__ X,
                                                 const float* __restrict__ T,
                                                 const __bf16* __restrict__ Wt,
                                                 const float* __restrict__ Bb,
                                                 float* __restrict__ Out) {
  __shared__ float As[3][128 * 32];  // 16 KB each, 48 KB total

  // XCD-chunked remap: keeps logical twins (2p,2p+1) on one XCD's L2.
  const int bid = blockIdx.x;
  const int wg  = ((bid & 7) << 8) | (bid >> 3);
  const int c   = wg >> 5;
  const int mg  = (wg >> 1) & 15;
  const int nt  = wg & 1;
  const int n0  = nt * 128;
  const int m0  = mg * 128;

  const int tid  = threadIdx.x;
  const int lane = tid & 63;
  const int w    = tid >> 6;
  const int wm   = w & 1;      // 2x2 wave grid
  const int wn   = w >> 1;
  const int r    = lane & 15;  // fragment row/col
  const int kg   = lane >> 4;  // k-group 0..3

  const float*  __restrict__ Xc = X  + (size_t)c * (M_PTS * K_DIM);
  const __bf16* __restrict__ Wc = Wt + (size_t)c * (K_DIM * N_DIM);

  // staging: wave w rows [w*32, w*32+32), 4 issues of 8 rows x 128B.
  // Source chunk pre-permuted (lc^l8) so the swizzled read finds its data.
  const int l8 = lane >> 3;
  const int lc = lane & 7;
  const float* __restrict__ xbase =
      Xc + (size_t)(m0 + w * 32 + l8) * K_DIM + ((lc ^ l8) << 2);
  const int lbase = (w * 32 + l8) * 32 + lc * 4;  // float index into As[buf]

#define STAGE(kt_, buf_)                                                      \
  {                                                                           \
    _Pragma("unroll") for (int u = 0; u < 4; ++u) {                           \
      __builtin_amdgcn_global_load_lds(                                       \
          (gbl_void*)(xbase + (size_t)u * 8 * K_DIM + (kt_) * 32),            \
          (lds_void*)(&As[buf_][lbase + u * 256]), 16, 0, 0);                 \
    }                                                                         \
  }

  // B fragment pointers: Wt row (n) is K-contiguous bf16; 16B per (j,kt).
  const __bf16* __restrict__ wb[4];
#pragma unroll
  for (int j = 0; j < 4; ++j)
    wb[j] = Wc + (size_t)(n0 + wn * 64 + j * 16 + r) * K_DIM + kg * 8;

  floatx4 acc[4][4] = {};
  uintx4 b0[4], b1[4];

  // ---- prologue: STAGE(0), STAGE(1), B(0) -- pinned order ----
  STAGE(0, 0);
  asm volatile("" ::: "memory");
  STAGE(1, 1);
  asm volatile("" ::: "memory");
#pragma unroll
  for (int j = 0; j < 4; ++j)
    asm volatile("global_load_dwordx4 %0, %1, off"
                 : "=&v"(b0[j]) : "v"(wb[j]) : "memory");

  // ---- 8 hand-unrolled steps with static counted waits ----
#define STEP(s_, VTOP_, VMFMA_, BC_, BN_)                                     \
  {                                                                           \
    asm volatile("s_waitcnt vmcnt(" #VTOP_ ") lgkmcnt(0)" ::: "memory");      \
    __builtin_amdgcn_sched_barrier(0);                                        \
    __builtin_amdgcn_s_barrier();                                             \
    __builtin_amdgcn_sched_barrier(0);                                        \
    if ((s_) + 2 < 8) STAGE((s_) + 2, ((s_) + 2) % 3);                        \
    asm volatile("" ::: "memory");                                            \
    if ((s_) + 1 < 8) {                                                       \
      _Pragma("unroll") for (int j = 0; j < 4; ++j)                           \
        asm volatile("global_load_dwordx4 %0, %1, off"                        \
                     : "=&v"(BN_[j])                                          \
                     : "v"(wb[j] + ((s_) + 1) * 32) : "memory");              \
    }                                                                         \
    const float* __restrict__ Ab = As[(s_) % 3];                              \
    floatx4 f0[4], f1[4];                                                     \
    _Pragma("unroll") for (int i = 0; i < 4; ++i) {                           \
      const int row_ = wm * 64 + i * 16 + r;                                  \
      const int p0_  = ((kg * 32) ^ ((r & 7) << 4)) >> 2;                     \
      f0[i] = *(const floatx4*)&Ab[row_ * 32 + p0_];                          \
      f1[i] = *(const floatx4*)&Ab[row_ * 32 + (p0_ ^ 4)];                    \
    }                                                                         \
    asm volatile("s_waitcnt vmcnt(" #VMFMA_ ") lgkmcnt(0)" ::: "memory");     \
    __builtin_amdgcn_sched_barrier(0);                                        \
    _Pragma("unroll") for (int i = 0; i < 4; ++i) {                           \
      uintx4 q;                                                               \
      q.x = cvt_pk(f0[i].x, f0[i].y);                                         \
      q.y = cvt_pk(f0[i].z, f0[i].w);                                         \
      q.z = cvt_pk(f1[i].x, f1[i].y);                                         \
      q.w = cvt_pk(f1[i].z, f1[i].w);                                         \
      const bf16x8 av = __builtin_bit_cast(bf16x8, q);                        \
      _Pragma("unroll") for (int j = 0; j < 4; ++j)                           \
        acc[i][j] = __builtin_amdgcn_mfma_f32_16x16x32_bf16(                  \
            av, __builtin_bit_cast(bf16x8, BC_[j]), acc[i][j], 0, 0, 0);      \
    }                                                                         \
  }

  STEP(0,  8, 8, b0, b1);
  STEP(1, 12, 8, b1, b0);
  STEP(2, 12, 8, b0, b1);
  STEP(3, 12, 8, b1, b0);
  STEP(4, 12, 8, b0, b1);
  STEP(5, 12, 8, b1, b0);
  STEP(6, 12, 4, b0, b1);
  STEP(7,  8, 0, b1, b0);
#undef STEP
#undef STAGE

  // ---- epilogue: bias loads here (keeps loop vmcnt counts clean) ----
  int bidx = (int)(T[c] * 31.0f);
  bidx = bidx < 0 ? 0 : (bidx > 31 ? 31 : bidx);
  const float* __restrict__ brow = Bb + bidx * N_DIM + n0 + wn * 64;
  float bv[4];
#pragma unroll
  for (int j = 0; j < 4; ++j) bv[j] = brow[j * 16 + r];

  // C/D layout: col=lane&15, row=(lane>>4)*4+reg [m89/m91]
  float* __restrict__ Oc = Out + (size_t)c * (M_PTS * N_DIM);
#pragma unroll
  for (int i = 0; i < 4; ++i) {
#pragma unroll
    for (int j = 0; j < 4; ++j) {
      const int col = n0 + wn * 64 + j * 16 + r;
#pragma unroll
      for (int v = 0; v < 4; ++v) {
        const int row = m0 + wm * 64 + i * 16 + kg * 4 + v;
        Oc[(size_t)row * N_DIM + col] = acc[i][j][v] + bv[j];
      }
    }
  }
}

// ---- fallback: previous proven kernel (used only if workspace too small) ---
__global__ __launch_bounds__(256) void fused_k(
    const float* __restrict__ X, const float* __restrict__ T,
    const int* __restrict__ MI, const float* __restrict__ W,
    const float* __restrict__ Bb, float* __restrict__ Out) {
  __shared__ __bf16 As[128 * 32];
  __shared__ __bf16 Bt[128 * BT_STRIDE];

  const int bid = blockIdx.x;
  const int c   = bid >> 4;
  const int mg  = (bid >> 1) & 7;
  const int nt  = bid & 1;
  const int n0  = nt * 128;

  const float* __restrict__ Xc = X + (size_t)c * (M_PTS * K_DIM);
  const float* __restrict__ Wc = W + (size_t)MI[c] * (K_DIM * N_DIM);

  const int tid  = threadIdx.x;
  const int lane = tid & 63;
  const int w    = tid >> 6;
  const int wm   = w & 1;
  const int wn   = w >> 1;
  const int r    = lane & 15;
  const int kg   = lane >> 4;

  {
    const int n  = tid & 127;
    const int kq = tid >> 7;
    const float* __restrict__ src = Wc + (size_t)(kq * 128) * N_DIM + n0 + n;
    __bf16* __restrict__ dst = &Bt[n * BT_STRIDE + kq * 128];
#pragma unroll 4
    for (int u = 0; u < 32; ++u) {
      bf16x4 v;
      v.x = cvt_bf16(src[(size_t)(u * 4 + 0) * N_DIM]);
      v.y = cvt_bf16(src[(size_t)(u * 4 + 1) * N_DIM]);
      v.z = cvt_bf16(src[(size_t)(u * 4 + 2) * N_DIM]);
      v.w = cvt_bf16(src[(size_t)(u * 4 + 3) * N_DIM]);
      *(bf16x4*)&dst[u * 4] = v;
    }
  }

  const int sm  = tid >> 1;
  const int skh = (tid & 1) * 16;
  const float* __restrict__ xrow = Xc + skh;
  __bf16* __restrict__ adst = &As[sm * 32 + skh];

  int bidx = (int)(T[c] * 31.0f);
  bidx = bidx < 0 ? 0 : (bidx > 31 ? 31 : bidx);
  const float* __restrict__ brow = Bb + bidx * N_DIM + n0 + wn * 64;
  float bv[4];
#pragma unroll
  for (int j = 0; j < 4; ++j) bv[j] = brow[j * 16 + r];

  float* __restrict__ Oc = Out + (size_t)c * (M_PTS * N_DIM);

  for (int mt2 = 0; mt2 < 2; ++mt2) {
    const int m0 = mg * 256 + mt2 * 128;
    const float* __restrict__ xsrc = xrow + (size_t)(m0 + sm) * K_DIM;
    floatx4 acc[4][4] = {};

    for (int kt = 0; kt < 8; ++kt) {
      const int k0 = kt * 32;
      __syncthreads();
      {
        floatx4 f0 = *(const floatx4*)(xsrc + k0 + 0);
        floatx4 f1 = *(const floatx4*)(xsrc + k0 + 4);
        floatx4 f2 = *(const floatx4*)(xsrc + k0 + 8);
        floatx4 f3 = *(const floatx4*)(xsrc + k0 + 12);
        bf16x8 h0, h1;
#pragma unroll
        for (int v = 0; v < 4; ++v) {
          h0[v]     = cvt_bf16(f0[v]);
          h0[v + 4] = cvt_bf16(f1[v]);
          h1[v]     = cvt_bf16(f2[v]);
          h1[v + 4] = cvt_bf16(f3[v]);
        }
        *(bf16x8*)&adst[0] = h0;
        *(bf16x8*)&adst[8] = h1;
      }
      __syncthreads();

      bf16x8 a[4], b[4];
#pragma unroll
      for (int i = 0; i < 4; ++i)
        a[i] = *(const bf16x8*)&As[(wm * 64 + i * 16 + r) * 32 + kg * 8];
#pragma unroll
      for (int j = 0; j < 4; ++j)
        b[j] = *(const bf16x8*)&Bt[(wn * 64 + j * 16 + r) * BT_STRIDE + k0 + kg * 8];
#pragma unroll
      for (int i = 0; i < 4; ++i)
#pragma unroll
        for (int j = 0; j < 4; ++j)
          acc[i][j] = __builtin_amdgcn_mfma_f32_16x16x32_bf16(a[i], b[j], acc[i][j], 0, 0, 0);
    }

#pragma unroll
    for (int i = 0; i < 4; ++i) {
#pragma unroll
      for (int j = 0; j < 4; ++j) {
        const int col = n0 + wn * 64 + j * 16 + r;
#pragma unroll
        for (int v = 0; v < 4; ++v) {
          const int row = m0 + wm * 64 + i * 16 + kg * 4 + v;
          Oc[(size_t)row * N_DIM + col] = acc[i][j][v] + bv[j];
        }
      }
    }
  }
}

extern "C" void kernel_launch(void* const* d_in, const int* in_sizes, int n_in,
                              void* d_out, int out_size, void* d_ws, size_t ws_size,
                              hipStream_t stream) {
  const float* X   = (const float*)d_in[0];  // x [64,2048,256]
  const float* T   = (const float*)d_in[1];  // t [64]
  const int* MI    = (const int*)d_in[2];    // model_idx [64]
  const float* W   = (const float*)d_in[3];  // W [64,256,256]
  const float* Bb  = (const float*)d_in[4];  // B [32,256]
  float* Out       = (float*)d_out;

  if (ws_size >= WT_BYTES && d_ws != nullptr) {
    __bf16* Wt = (__bf16*)d_ws;
    wt_k<<<dim3(1024), dim3(256), 0, stream>>>(W, MI, Wt);
    gemm_k<<<dim3(2048), dim3(256), 0, stream>>>(X, T, Wt, Bb, Out);
  } else {
    fused_k<<<dim3(1024), dim3(256), 0, stream>>>(X, T, MI, W, Bb, Out);
  }
}